// Round 1
// baseline (247.206 us; speedup 1.0000x reference)
//
#include <hip/hip_runtime.h>
#include <math.h>

// Problem constants (match reference)
#define NB 16       // batch
#define NL 512      // rows per batch
#define NS 512      // samples per row
#define NE 3000     // ecdf grid points (3*N_REF)
#define NR 1000     // ref points
#define NROWS (NB * NL)

// bisect_left == jnp.searchsorted(side='left') on sorted data
__device__ __forceinline__ int bisect_left(const float* arr, int n, float q) {
    int lo = 0, hi = n;
    while (lo < hi) {
        int mid = (lo + hi) >> 1;
        if (arr[mid] < q) lo = mid + 1; else hi = mid;
    }
    return lo;
}

__global__ __launch_bounds__(256) void lcot_row_kernel(
    const float* __restrict__ x1, const float* __restrict__ x2,
    const float* __restrict__ ref, float* __restrict__ row_out)
{
    __shared__ float s_samp[NS];
    __shared__ float s_ecdf[NE];
    __shared__ float s_e1[NR];
    __shared__ float s_red[256];
    __shared__ float s_alpha;

    const int row = blockIdx.x;
    const int tid = threadIdx.x;
    const float inv_n = 1.0f / (float)NS;          // ys spacing, exact in fp32
    const float step = (float)(3.0 / 2999.0);      // linspace(-1,2,3000) spacing

    float acc = 0.0f;

    for (int inp = 0; inp < 2; ++inp) {
        const float* src = (inp == 0 ? x1 : x2) + (size_t)row * NS;

        // ---- load row + partial sum for alpha ----
        float v0 = src[tid];
        float v1 = src[tid + 256];
        s_samp[tid] = v0;
        s_samp[tid + 256] = v1;
        s_red[tid] = v0 + v1;
        __syncthreads();
        for (int off = 128; off > 0; off >>= 1) {
            if (tid < off) s_red[tid] += s_red[tid + off];
            __syncthreads();
        }
        if (tid == 0) s_alpha = s_red[0] * inv_n - 0.5f;

        // ---- bitonic sort 512 elements in LDS (ascending) ----
        for (int k = 2; k <= NS; k <<= 1) {
            for (int j = k >> 1; j > 0; j >>= 1) {
                __syncthreads();
                #pragma unroll
                for (int base = 0; base < NS; base += 256) {
                    int idx = base + tid;
                    int ixj = idx ^ j;
                    if (ixj > idx) {
                        float a = s_samp[idx];
                        float b = s_samp[ixj];
                        bool up = ((idx & k) == 0);
                        if ((a > b) == up) { s_samp[idx] = b; s_samp[ixj] = a; }
                    }
                }
            }
        }
        __syncthreads();

        // ---- circular ECDF on the 3000-point grid ----
        for (int kk = tid; kk < NE; kk += 256) {
            float xnew = -1.0f + (float)kk * step;
            float ix   = floorf(xnew);
            float rest = xnew - ix;
            int pos = bisect_left(s_samp, NS, rest);
            int i = min(max(pos - 1, 0), NS - 2);
            float x0 = s_samp[i];
            float y0 = (float)(i + 1) * inv_n;
            float slope = inv_n / (s_samp[i + 1] - x0);   // (ys[i+1]-ys[i]) == 1/512 exactly
            s_ecdf[kk] = ix + (y0 + slope * (rest - x0));
        }
        __syncthreads();

        // ---- inverse CDF at ref[j] - alpha, minus identity ----
        float alpha = s_alpha;
        for (int j = tid; j < NR; j += 256) {
            float rj = ref[j];
            float q = rj - alpha;
            int pos = bisect_left(s_ecdf, NE, q);
            int i = min(max(pos - 1, 0), NE - 2);
            float e0 = s_ecdf[i];
            float slope = step / (s_ecdf[i + 1] - e0);    // (xnew[i+1]-xnew[i]) == step
            float xn0 = -1.0f + (float)i * step;
            float res = xn0 + slope * (q - e0);
            float embv = res - rj;
            if (inp == 0) {
                s_e1[j] = embv;
            } else {
                float d = fabsf(embv - s_e1[j]);
                float c = fminf(d, 1.0f - d);
                acc = fmaf(c, c, acc);
            }
        }
        __syncthreads();   // protect s_ecdf/s_samp/s_red before next input reuses them
    }

    // ---- block reduce acc, sqrt, write per-row ----
    s_red[tid] = acc;
    __syncthreads();
    for (int off = 128; off > 0; off >>= 1) {
        if (tid < off) s_red[tid] += s_red[tid + off];
        __syncthreads();
    }
    if (tid == 0) row_out[row] = sqrtf(s_red[0]);
}

__global__ __launch_bounds__(256) void lcot_reduce_kernel(
    const float* __restrict__ row_vals, float* __restrict__ out)
{
    __shared__ float s_red[256];
    const int b = blockIdx.x;
    const int tid = threadIdx.x;
    float v = row_vals[b * NL + tid] + row_vals[b * NL + tid + 256];
    s_red[tid] = v;
    __syncthreads();
    for (int off = 128; off > 0; off >>= 1) {
        if (tid < off) s_red[tid] += s_red[tid + off];
        __syncthreads();
    }
    if (tid == 0) out[b] = s_red[0] * (1.0f / (float)NL);
}

extern "C" void kernel_launch(void* const* d_in, const int* in_sizes, int n_in,
                              void* d_out, int out_size, void* d_ws, size_t ws_size,
                              hipStream_t stream) {
    const float* x1  = (const float*)d_in[0];
    const float* x2  = (const float*)d_in[1];
    const float* ref = (const float*)d_in[2];
    float* out = (float*)d_out;
    float* row_vals = (float*)d_ws;   // NROWS floats of scratch

    lcot_row_kernel<<<NROWS, 256, 0, stream>>>(x1, x2, ref, row_vals);
    lcot_reduce_kernel<<<NB, 256, 0, stream>>>(row_vals, out);
}

// Round 2
// 151.817 us; speedup vs baseline: 1.6283x; 1.6283x over previous
//
#include <hip/hip_runtime.h>
#include <math.h>

// Problem constants (match reference)
#define NB 16       // batch
#define NL 512      // rows per batch
#define NS 512      // samples per row
#define NE 3000     // ecdf grid points (3*N_REF)
#define NR 1000     // ref points
#define NROWS (NB * NL)
#define NBIN 512    // counting-sort bins (avg 1 sample/bin)

__global__ __launch_bounds__(256) void lcot_row_kernel(
    const float* __restrict__ x1, const float* __restrict__ x2,
    const float* __restrict__ ref, float* __restrict__ row_out)
{
    __shared__ float    s_sorted[NS];
    __shared__ unsigned s_hist[NBIN];       // histogram, then scatter cursor
    __shared__ unsigned s_prefix[NBIN + 1]; // exclusive prefix (stable)
    __shared__ float    s_ecdf[NE];
    __shared__ float    s_e1[NR];
    __shared__ float    s_wredf[4];         // alpha partials per wave
    __shared__ unsigned s_wredu[4];         // prefix-scan wave totals

    const int tid  = threadIdx.x;
    const int lane = tid & 63;
    const int wave = tid >> 6;
    const int row  = blockIdx.x;
    const float inv_n = 1.0f / 512.0f;              // exact
    const float step  = (float)(3.0 / 2999.0);      // same expr as round-1 (bitwise match)

    // preload this thread's 4 query refs once (j0 = 4*tid; threads 250..255 idle)
    const int j0 = tid * 4;
    float rj0 = 0.f, rj1 = 0.f, rj2 = 0.f, rj3 = 0.f;
    if (j0 < NR) {
        float4 r4 = ((const float4*)ref)[tid];
        rj0 = r4.x; rj1 = r4.y; rj2 = r4.z; rj3 = r4.w;
    }

    float acc = 0.0f;

    for (int inp = 0; inp < 2; ++inp) {
        const float* src = (inp == 0 ? x1 : x2) + (size_t)row * NS;
        float v0 = src[tid];
        float v1 = src[tid + 256];

        // ---- zero histogram + alpha wave-partials ----
        s_hist[tid] = 0u;
        s_hist[tid + 256] = 0u;
        float s = v0 + v1;
        #pragma unroll
        for (int o = 32; o > 0; o >>= 1) s += __shfl_down(s, o, 64);
        if (lane == 0) s_wredf[wave] = s;
        __syncthreads();                                   // (A)

        // ---- histogram ----
        int b0 = min((int)(v0 * 512.0f), NBIN - 1);
        int b1 = min((int)(v1 * 512.0f), NBIN - 1);
        atomicAdd(&s_hist[b0], 1u);
        atomicAdd(&s_hist[b1], 1u);
        __syncthreads();                                   // (B)

        float alpha = (s_wredf[0] + s_wredf[1] + s_wredf[2] + s_wredf[3]) * inv_n - 0.5f;

        // ---- exclusive prefix over 512 bins (2 consecutive bins / thread) ----
        unsigned h0 = s_hist[2 * tid];
        unsigned h1 = s_hist[2 * tid + 1];
        unsigned ls = h0 + h1;
        unsigned sc = ls;                                  // wave inclusive scan
        #pragma unroll
        for (int o = 1; o < 64; o <<= 1) {
            unsigned t2 = __shfl_up(sc, o, 64);
            if (lane >= o) sc += t2;
        }
        if (lane == 63) s_wredu[wave] = sc;
        __syncthreads();                                   // (C)
        unsigned wbase = 0;
        for (int w = 0; w < 4; ++w) if (w < wave) wbase += s_wredu[w];
        unsigned base = wbase + sc - ls;                   // exclusive base for bin 2*tid
        s_prefix[2 * tid]     = base;
        s_prefix[2 * tid + 1] = base + h0;
        s_hist[2 * tid]       = base;                      // scatter cursors
        s_hist[2 * tid + 1]   = base + h0;
        if (tid == 255) s_prefix[NBIN] = (unsigned)NS;
        __syncthreads();                                   // (D)

        // ---- scatter ----
        unsigned p0 = atomicAdd(&s_hist[b0], 1u);
        s_sorted[p0] = v0;
        unsigned p1 = atomicAdd(&s_hist[b1], 1u);
        s_sorted[p1] = v1;
        __syncthreads();                                   // (E)

        // ---- per-bin insertion sort (exact; bins avg 1 element) ----
        #pragma unroll
        for (int bb = tid; bb < NBIN; bb += 256) {
            int beg = (int)s_prefix[bb];
            int end = (int)s_prefix[bb + 1];
            for (int i2 = beg + 1; i2 < end; ++i2) {
                float key = s_sorted[i2];
                int jj = i2 - 1;
                while (jj >= beg && s_sorted[jj] > key) { s_sorted[jj + 1] = s_sorted[jj]; --jj; }
                s_sorted[jj + 1] = key;
            }
        }
        __syncthreads();                                   // (F)

        // ---- ECDF on 3000-point grid: contiguous chunk per thread, running pos ----
        {
            int k0 = (tid * NE) >> 8;            // tid*3000/256
            int k1 = ((tid + 1) * NE) >> 8;
            float fm = -100.0f;                  // force re-seed on first iter
            int pos = 0;
            int ci = -1;
            float cx0 = 0.f, cy0 = 0.f, cslope = 0.f;
            for (int k = k0; k < k1; ++k) {
                float xn  = -1.0f + (float)k * step;   // identical expr to reference-matching code
                float fm2 = floorf(xn);
                float r   = xn - fm2;
                if (fm2 != fm) {
                    // new integer segment: re-seed pos from bin table
                    fm = fm2;
                    int bq  = min((int)(r * 512.0f), NBIN - 1);
                    pos     = (int)s_prefix[bq];
                    int be  = (int)s_prefix[bq + 1];
                    while (pos < be && s_sorted[pos] < r) ++pos;
                } else {
                    while (pos < NS && s_sorted[pos] < r) ++pos;
                }
                int i = min(max(pos - 1, 0), NS - 2);
                if (i != ci) {
                    ci = i;
                    cx0 = s_sorted[i];
                    cy0 = (float)(i + 1) * inv_n;
                    cslope = inv_n / (s_sorted[i + 1] - cx0);
                }
                s_ecdf[k] = fm + (cy0 + cslope * (r - cx0));
            }
        }
        __syncthreads();                                   // (G)

        // ---- inverse CDF at 4 contiguous queries/thread ----
        if (j0 < NR) {
            float q = rj0 - alpha;
            int lo = 0, hi = NE;
            while (lo < hi) {                               // bisect_left for first query
                int mid = (lo + hi) >> 1;
                if (s_ecdf[mid] < q) lo = mid + 1; else hi = mid;
            }
            int pos2 = lo;
            #pragma unroll
            for (int jj = 0; jj < 4; ++jj) {
                float rj = (jj == 0) ? rj0 : (jj == 1) ? rj1 : (jj == 2) ? rj2 : rj3;
                q = rj - alpha;
                if (jj > 0) while (pos2 < NE && s_ecdf[pos2] < q) ++pos2;
                int i = min(max(pos2 - 1, 0), NE - 2);
                float e0 = s_ecdf[i];
                float slope = step / (s_ecdf[i + 1] - e0);
                float xn0 = -1.0f + (float)i * step;
                float res = xn0 + slope * (q - e0);
                float embv = res - rj;
                int j = j0 + jj;
                if (inp == 0) {
                    s_e1[j] = embv;
                } else {
                    float d = fabsf(embv - s_e1[j]);
                    float c = fminf(d, 1.0f - d);
                    acc = fmaf(c, c, acc);
                }
            }
        }
        __syncthreads();                                   // (H) protect LDS before next input
    }

    // ---- block reduce acc, sqrt, write per-row ----
    #pragma unroll
    for (int o = 32; o > 0; o >>= 1) acc += __shfl_down(acc, o, 64);
    if (lane == 0) s_wredf[wave] = acc;
    __syncthreads();
    if (tid == 0) row_out[row] = sqrtf(s_wredf[0] + s_wredf[1] + s_wredf[2] + s_wredf[3]);
}

__global__ __launch_bounds__(256) void lcot_reduce_kernel(
    const float* __restrict__ row_vals, float* __restrict__ out)
{
    __shared__ float s_red[256];
    const int b = blockIdx.x;
    const int tid = threadIdx.x;
    float v = row_vals[b * NL + tid] + row_vals[b * NL + tid + 256];
    s_red[tid] = v;
    __syncthreads();
    for (int off = 128; off > 0; off >>= 1) {
        if (tid < off) s_red[tid] += s_red[tid + off];
        __syncthreads();
    }
    if (tid == 0) out[b] = s_red[0] * (1.0f / (float)NL);
}

extern "C" void kernel_launch(void* const* d_in, const int* in_sizes, int n_in,
                              void* d_out, int out_size, void* d_ws, size_t ws_size,
                              hipStream_t stream) {
    const float* x1  = (const float*)d_in[0];
    const float* x2  = (const float*)d_in[1];
    const float* ref = (const float*)d_in[2];
    float* out = (float*)d_out;
    float* row_vals = (float*)d_ws;   // NROWS floats of scratch

    lcot_row_kernel<<<NROWS, 256, 0, stream>>>(x1, x2, ref, row_vals);
    lcot_reduce_kernel<<<NB, 256, 0, stream>>>(row_vals, out);
}

// Round 3
// 106.286 us; speedup vs baseline: 2.3259x; 1.4284x over previous
//
#include <hip/hip_runtime.h>
#include <math.h>

// Problem constants (match reference)
#define NB 16       // batch
#define NL 512      // rows per batch
#define NS 512      // samples per row
#define NE 3000     // ecdf grid points (3*N_REF)
#define NR 1000     // ref points
#define NROWS (NB * NL)
#define NBIN 512    // counting-sort bins (avg 1 sample/bin)

__device__ __forceinline__ float fast_rcp(float x) { return __builtin_amdgcn_rcpf(x); }

__global__ __launch_bounds__(256) void lcot_row_kernel(
    const float* __restrict__ x1, const float* __restrict__ x2,
    const float* __restrict__ ref, float* __restrict__ row_out)
{
    __shared__ float    s_sorted[NS];
    __shared__ unsigned s_hist[NBIN];       // histogram, then scatter cursor
    __shared__ unsigned s_prefix[NBIN + 1]; // exclusive prefix (stable)
    __shared__ float    s_ecdf[NE];
    __shared__ float    s_wredf[4];         // per-wave float partials (alpha, dev, acc)
    __shared__ unsigned s_wredu[4];         // prefix-scan wave totals

    const int tid  = threadIdx.x;
    const int lane = tid & 63;
    const int wave = tid >> 6;
    const int row  = blockIdx.x;
    const float inv_n   = 1.0f / 512.0f;            // exact
    const float step    = (float)(3.0 / 2999.0);    // linspace(-1,2,3000) spacing
    const float invstep = 2999.0f / 3.0f;

    // preload this thread's 4 query refs once (j0 = 4*tid; threads 250..255 idle)
    const int j0 = tid * 4;
    float rj0 = 0.f, rj1 = 0.f, rj2 = 0.f, rj3 = 0.f;
    if (j0 < NR) {
        float4 r4 = ((const float4*)ref)[tid];
        rj0 = r4.x; rj1 = r4.y; rj2 = r4.z; rj3 = r4.w;
    }
    float e1r0 = 0.f, e1r1 = 0.f, e1r2 = 0.f, e1r3 = 0.f;   // e1 kept in registers

    float acc = 0.0f;

    for (int inp = 0; inp < 2; ++inp) {
        const float* src = (inp == 0 ? x1 : x2) + (size_t)row * NS;
        float v0 = src[tid];
        float v1 = src[tid + 256];

        // ---- zero histogram + alpha wave-partials ----
        s_hist[tid] = 0u;
        s_hist[tid + 256] = 0u;
        float s = v0 + v1;
        #pragma unroll
        for (int o = 32; o > 0; o >>= 1) s += __shfl_down(s, o, 64);
        if (lane == 0) s_wredf[wave] = s;
        __syncthreads();                                   // (A)

        // ---- histogram ----
        int b0 = min((int)(v0 * 512.0f), NBIN - 1);
        int b1 = min((int)(v1 * 512.0f), NBIN - 1);
        atomicAdd(&s_hist[b0], 1u);
        atomicAdd(&s_hist[b1], 1u);
        __syncthreads();                                   // (B)

        float alpha = (s_wredf[0] + s_wredf[1] + s_wredf[2] + s_wredf[3]) * inv_n - 0.5f;

        // ---- exclusive prefix over 512 bins (2 consecutive bins / thread) ----
        unsigned h0 = s_hist[2 * tid];
        unsigned h1 = s_hist[2 * tid + 1];
        unsigned ls = h0 + h1;
        unsigned sc = ls;                                  // wave inclusive scan
        #pragma unroll
        for (int o = 1; o < 64; o <<= 1) {
            unsigned t2 = __shfl_up(sc, o, 64);
            if (lane >= o) sc += t2;
        }
        if (lane == 63) s_wredu[wave] = sc;
        __syncthreads();                                   // (C)
        unsigned wbase = 0;
        for (int w = 0; w < 4; ++w) if (w < wave) wbase += s_wredu[w];
        unsigned base = wbase + sc - ls;                   // exclusive base for bin 2*tid
        s_prefix[2 * tid]     = base;
        s_prefix[2 * tid + 1] = base + h0;
        s_hist[2 * tid]       = base;                      // scatter cursors
        s_hist[2 * tid + 1]   = base + h0;
        if (tid == 255) s_prefix[NBIN] = (unsigned)NS;
        __syncthreads();                                   // (D)

        // ---- scatter ----
        unsigned p0 = atomicAdd(&s_hist[b0], 1u);
        s_sorted[p0] = v0;
        unsigned p1 = atomicAdd(&s_hist[b1], 1u);
        s_sorted[p1] = v1;
        __syncthreads();                                   // (E)

        // ---- per-bin insertion sort (exact; bins avg 1 element) ----
        for (int bb = tid; bb < NBIN; bb += 256) {
            int beg = (int)s_prefix[bb];
            int end = (int)s_prefix[bb + 1];
            for (int i2 = beg + 1; i2 < end; ++i2) {
                float key = s_sorted[i2];
                int jj = i2 - 1;
                while (jj >= beg && s_sorted[jj] > key) { s_sorted[jj + 1] = s_sorted[jj]; --jj; }
                s_sorted[jj + 1] = key;
            }
        }
        __syncthreads();                                   // (F)

        // ---- exact deviation bound D = max|ECDF chord - identity| ----
        float dev = fmaxf(fabsf((float)(tid + 1)   * inv_n - s_sorted[tid]),
                          fabsf((float)(tid + 257) * inv_n - s_sorted[tid + 256]));
        #pragma unroll
        for (int o = 32; o > 0; o >>= 1) dev = fmaxf(dev, __shfl_down(dev, o, 64));
        if (lane == 0) s_wredf[wave] = dev;
        __syncthreads();                                   // (F2)
        float Dm = fmaxf(fmaxf(s_wredf[0], s_wredf[1]), fmaxf(s_wredf[2], s_wredf[3]));
        {   // extrapolation endpoint deviations (chord 0 at r=0, chord 510 at r=1)
            float sa0 = s_sorted[0], sa1 = s_sorted[1];
            float sbA = s_sorted[510], sbB = s_sorted[511];
            float sl0 = inv_n * fast_rcp(sa1 - sa0);
            float slR = inv_n * fast_rcp(sbB - sbA);
            float lext = fabsf(inv_n - sl0 * sa0);
            float rext = fabsf(511.0f * inv_n + slR * (1.0f - sbA) - 1.0f);
            Dm = fmaxf(Dm, fmaxf(lext, rext));
        }
        float D = Dm + 1.5e-3f;                            // fp slop margin (> 1 grid step)

        float qlo = 0.0f - alpha;
        float qhi = 0.999f - alpha;
        int kmin = max(0,  (int)((qlo + 1.0f - D) * invstep) - 2);
        int kmax = min(NE, (int)((qhi + 1.0f + D) * invstep) + 3);

        // ---- ECDF on window [kmin,kmax): contiguous chunk per thread, running pos ----
        {
            int W  = kmax - kmin;
            int k0 = kmin + ((tid * W) >> 8);
            int k1 = kmin + (((tid + 1) * W) >> 8);
            float fm = -100.0f;                  // force re-seed on first iter
            int pos = 0;
            int ci = -1;
            float cx0 = 0.f, cy0 = 0.f, cslope = 0.f;
            for (int k = k0; k < k1; ++k) {
                float xn  = -1.0f + (float)k * step;
                float fm2 = floorf(xn);
                float r   = xn - fm2;
                if (fm2 != fm) {
                    fm = fm2;
                    int bq  = min((int)(r * 512.0f), NBIN - 1);
                    pos     = (int)s_prefix[bq];
                    int be  = (int)s_prefix[bq + 1];
                    while (pos < be && s_sorted[pos] < r) ++pos;
                } else {
                    while (pos < NS && s_sorted[pos] < r) ++pos;
                }
                int i = min(max(pos - 1, 0), NS - 2);
                if (i != ci) {
                    ci = i;
                    cx0 = s_sorted[i];
                    cy0 = (float)(i + 1) * inv_n;
                    cslope = inv_n * fast_rcp(s_sorted[i + 1] - cx0);
                }
                s_ecdf[k] = fm + (cy0 + cslope * (r - cx0));
            }
        }
        __syncthreads();                                   // (G)

        // ---- inverse CDF at 4 contiguous queries/thread (search only the window) ----
        if (j0 < NR) {
            float q = rj0 - alpha;
            int lo = kmin, hi = kmax;
            while (lo < hi) {                               // bisect_left
                int mid = (lo + hi) >> 1;
                if (s_ecdf[mid] < q) lo = mid + 1; else hi = mid;
            }
            int pos2 = lo;
            #pragma unroll
            for (int jj = 0; jj < 4; ++jj) {
                float rj = (jj == 0) ? rj0 : (jj == 1) ? rj1 : (jj == 2) ? rj2 : rj3;
                q = rj - alpha;
                if (jj > 0) while (pos2 < NE && s_ecdf[pos2] < q) ++pos2;
                int i = min(max(pos2 - 1, 0), NE - 2);
                float e0 = s_ecdf[i];
                float slope = step * fast_rcp(s_ecdf[i + 1] - e0);
                float xn0 = -1.0f + (float)i * step;
                float res = xn0 + slope * (q - e0);
                float embv = res - rj;
                if (inp == 0) {
                    if (jj == 0) e1r0 = embv;
                    else if (jj == 1) e1r1 = embv;
                    else if (jj == 2) e1r2 = embv;
                    else e1r3 = embv;
                } else {
                    float e1v = (jj == 0) ? e1r0 : (jj == 1) ? e1r1 : (jj == 2) ? e1r2 : e1r3;
                    float d = fabsf(embv - e1v);
                    float c = fminf(d, 1.0f - d);
                    acc = fmaf(c, c, acc);
                }
            }
        }
        __syncthreads();                                   // (H) protect LDS before next input
    }

    // ---- block reduce acc, sqrt, write per-row ----
    #pragma unroll
    for (int o = 32; o > 0; o >>= 1) acc += __shfl_down(acc, o, 64);
    if (lane == 0) s_wredf[wave] = acc;
    __syncthreads();
    if (tid == 0) row_out[row] = sqrtf(s_wredf[0] + s_wredf[1] + s_wredf[2] + s_wredf[3]);
}

__global__ __launch_bounds__(256) void lcot_reduce_kernel(
    const float* __restrict__ row_vals, float* __restrict__ out)
{
    __shared__ float s_red[256];
    const int b = blockIdx.x;
    const int tid = threadIdx.x;
    float v = row_vals[b * NL + tid] + row_vals[b * NL + tid + 256];
    s_red[tid] = v;
    __syncthreads();
    for (int off = 128; off > 0; off >>= 1) {
        if (tid < off) s_red[tid] += s_red[tid + off];
        __syncthreads();
    }
    if (tid == 0) out[b] = s_red[0] * (1.0f / (float)NL);
}

extern "C" void kernel_launch(void* const* d_in, const int* in_sizes, int n_in,
                              void* d_out, int out_size, void* d_ws, size_t ws_size,
                              hipStream_t stream) {
    const float* x1  = (const float*)d_in[0];
    const float* x2  = (const float*)d_in[1];
    const float* ref = (const float*)d_in[2];
    float* out = (float*)d_out;
    float* row_vals = (float*)d_ws;   // NROWS floats of scratch

    lcot_row_kernel<<<NROWS, 256, 0, stream>>>(x1, x2, ref, row_vals);
    lcot_reduce_kernel<<<NB, 256, 0, stream>>>(row_vals, out);
}